// Round 6
// baseline (329.715 us; speedup 1.0000x reference)
//
#include <hip/hip_runtime.h>

#define N_ 16384
#define D_ 256
#define LOG2E 1.4426950408889634f
#define HEXP2(x) __builtin_amdgcn_exp2f(x)

typedef __attribute__((ext_vector_type(8))) short short8;
typedef __attribute__((ext_vector_type(16))) float floatx16;

typedef __attribute__((address_space(1))) const unsigned int gu32_t;
typedef __attribute__((address_space(3))) unsigned int lu32_t;

__device__ __forceinline__ void async16(const void* g, void* l) {
  __builtin_amdgcn_global_load_lds((gu32_t*)g, (lu32_t*)l, 16, 0, 0);
}

__device__ __forceinline__ unsigned short f2bf(float x) {
  unsigned int u = __float_as_uint(x);
  u += 0x7fffu + ((u >> 16) & 1u);
  return (unsigned short)(u >> 16);
}

// ---------------- prep: fp32 -> bf16 packed (write-coalesced) + fused exact diag ----------------
// (passed rounds 1, 2, 5)
__global__ void prep_pack(const float* __restrict__ img, const float* __restrict__ txt,
                          const float* __restrict__ ls, short* __restrict__ PA,
                          short* __restrict__ PB, float* __restrict__ diag2,
                          float* __restrict__ out) {
  const int tid = threadIdx.x;
  const int t = blockIdx.x * 1024 + tid;
  const int m = tid & 31, h = (tid >> 5) & 1, ks = (tid >> 6) & 15;
  const int G = blockIdx.x;
  const int row = G * 32 + m, col = ks * 16 + h * 8;
  const float s2 = ls[0] * LOG2E;
  const float4* sa = (const float4*)(img + (size_t)row * D_ + col);
  const float4* sb = (const float4*)(txt + (size_t)row * D_ + col);
  float4 a0 = sa[0], a1 = sa[1];
  float4 b0 = sb[0], b1 = sb[1];
  short8 oa, ob;
  oa[0] = (short)f2bf(a0.x * s2); oa[1] = (short)f2bf(a0.y * s2);
  oa[2] = (short)f2bf(a0.z * s2); oa[3] = (short)f2bf(a0.w * s2);
  oa[4] = (short)f2bf(a1.x * s2); oa[5] = (short)f2bf(a1.y * s2);
  oa[6] = (short)f2bf(a1.z * s2); oa[7] = (short)f2bf(a1.w * s2);
  ob[0] = (short)f2bf(b0.x); ob[1] = (short)f2bf(b0.y);
  ob[2] = (short)f2bf(b0.z); ob[3] = (short)f2bf(b0.w);
  ob[4] = (short)f2bf(b1.x); ob[5] = (short)f2bf(b1.y);
  ob[6] = (short)f2bf(b1.z); ob[7] = (short)f2bf(b1.w);
  ((short8*)PA)[t] = oa;
  ((short8*)PB)[t] = ob;

  float d = a0.x * b0.x + a0.y * b0.y + a0.z * b0.z + a0.w * b0.w
          + a1.x * b1.x + a1.y * b1.y + a1.z * b1.z + a1.w * b1.w;
  __shared__ float red[32][33];
  red[tid >> 5][m] = d;
  __syncthreads();
  if (tid < 32) {
    float s = 0.f;
    #pragma unroll
    for (int q = 0; q < 32; ++q) s += red[q][tid];
    diag2[G * 32 + tid] = s * s2;  // log2-domain scaled diagonal
  }
  if (t == 0) out[0] = 0.f;
}

// ---------------- gemm + stats: per-wave-private B staging, barrier-free phases ----------------
// Each wave stages ONLY its own 8 fragments per chunk (2 ctl x 4 ksl = 8KB) into its
// private LDS quarter (2 x 8KB dbuf). Phase loop is single-wave provable:
//   wait own vmcnt(8) -> compute (ds_read + MFMA) -> lgkmcnt(0) -> issue chunk n+2
//   into the buffer just consumed. No cross-wave edges on staged B; no phase barriers.
// Cost: 2x L2->LDS staging traffic (wr pair no longer shares B) -- far below L2 BW.
// Stats keeps the PROVEN 2-barrier pattern (write -> drain -> barrier -> read ->
// drain -> barrier) and round-5 msub semantics. rowbuf shrunk to [128][16 srcs]
// (stride 20) via 2-step shfl_xor partial butterfly so everything fits in 76KB.
// Barriers per tile: 10 -> 2.
__global__ __launch_bounds__(256, 2)
void gemm_stats(const short* __restrict__ PA, const short* __restrict__ PB,
                float2* __restrict__ pR, float2* __restrict__ pC) {
  __shared__ __align__(16) char smem[77824];
  // [0,65536): per-wave B staging: wave wv owns [wv*16384,+16384) = 2 bufs x 8KB,
  //            frag (ctl*4+ksl) at +1KB each
  // [65536,75776): rowbuf2 f32 [128 rows][stride 20] (srcs 0..15 used)
  // [75776,77824): colbuf float2[2 wr][128]
  float* rowbuf2 = (float*)(smem + 65536);
  float2* colbuf = (float2*)(smem + 75776);

  const int tid = threadIdx.x, lane = tid & 63, wv = tid >> 6;
  const int wr = wv >> 1, wc = wv & 1;
  const int m = lane & 31, h = lane >> 5;
  const int stripe = blockIdx.x, by = blockIdx.y;

  // ---- A panel into registers: rows stripe*128 + wr*64 .. +64, all K
  short8 areg[2][16];
  #pragma unroll
  for (int g = 0; g < 2; ++g)
    #pragma unroll
    for (int ks = 0; ks < 16; ++ks)
      areg[g][ks] = *(const short8*)(PA +
          ((size_t)((stripe * 4 + wr * 2 + g) * 16 + ks)) * 512 + lane * 8);
  asm volatile("s_waitcnt vmcnt(0)" ::: "memory");

  floatx16 acc[2][2];

  // stage chunk n (= jj*4+c2) for THIS wave only: frags (G = by*64+jj*4+wc*2+ctl,
  // ks = c2*4+ksl). Private dst, per-wave vmcnt. 8 async16 = 8KB.
  auto issue = [&](int n, int bufsel) {
    int jj2 = n >> 2, c2 = n & 3;
    const short* base = PB +
        ((size_t)((by * 64 + jj2 * 4 + wc * 2) * 16) + c2 * 4) * 512 + lane * 8;
    char* dst = smem + wv * 16384 + bufsel * 8192;
    #pragma unroll
    for (int ctl = 0; ctl < 2; ++ctl)
      #pragma unroll
      for (int ksl = 0; ksl < 4; ++ksl)
        async16(base + (size_t)(ctl * 16 + ksl) * 512, dst + (ctl * 4 + ksl) * 1024);
  };
  auto compute = [&](int c, int bufsel) {
    char* base = smem + wv * 16384 + bufsel * 8192 + lane * 16;
    #pragma unroll
    for (int ksl = 0; ksl < 4; ++ksl) {
      short8 b0 = *(const short8*)(base + (0 * 4 + ksl) * 1024);
      short8 b1 = *(const short8*)(base + (1 * 4 + ksl) * 1024);
      int ks = c * 4 + ksl;  // compile-time under unroll
      acc[0][0] = __builtin_amdgcn_mfma_f32_32x32x16_bf16(areg[0][ks], b0, acc[0][0], 0, 0, 0);
      acc[1][0] = __builtin_amdgcn_mfma_f32_32x32x16_bf16(areg[1][ks], b0, acc[1][0], 0, 0, 0);
      acc[0][1] = __builtin_amdgcn_mfma_f32_32x32x16_bf16(areg[0][ks], b1, acc[0][1], 0, 0, 0);
      acc[1][1] = __builtin_amdgcn_mfma_f32_32x32x16_bf16(areg[1][ks], b1, acc[1][1], 0, 0, 0);
    }
  };

  issue(0, 0);  // chunk 0 -> private buf 0
  issue(1, 1);  // chunk 1 -> private buf 1

  float Mr = -3.0e38f, Sr = 0.f;  // row LSE state: row = stripe*128 + wr*64 + wc*32 + m

  for (int jj = 0; jj < 16; ++jj) {
    #pragma unroll
    for (int rt = 0; rt < 2; ++rt)
      #pragma unroll
      for (int ctl = 0; ctl < 2; ++ctl)
        #pragma unroll
        for (int r = 0; r < 16; ++r) acc[rt][ctl][r] = 0.f;

    #pragma unroll
    for (int c = 0; c < 4; ++c) {
      int n = jj * 4 + c;
      // own chunk n in private buf c&1; own vmcnt: {n, n+1} outstanding (8 each)
      if (n == 63) { asm volatile("s_waitcnt vmcnt(0)" ::: "memory"); }
      else         { asm volatile("s_waitcnt vmcnt(8)" ::: "memory"); }
      compute(c, c & 1);
      // ensure all ds_reads of buf c&1 completed before DMA re-targets it
      asm volatile("s_waitcnt lgkmcnt(0)" ::: "memory");
      if (n + 2 < 64) issue(n + 2, c & 1);
    }

    // ---- stats. acc[rt][ctl][reg]: row(in tile) = wr*64+rt*32+(reg&3)+8*(reg>>2)+4*h
    //                                col(in tile) = wc*64+ctl*32+m
    float vm[4];
    #pragma unroll
    for (int q = 0; q < 4; ++q) {
      float a01 = fmaxf(acc[q >> 1][q & 1][0],  acc[q >> 1][q & 1][1]);
      float a23 = fmaxf(acc[q >> 1][q & 1][2],  acc[q >> 1][q & 1][3]);
      float a45 = fmaxf(acc[q >> 1][q & 1][4],  acc[q >> 1][q & 1][5]);
      float a67 = fmaxf(acc[q >> 1][q & 1][6],  acc[q >> 1][q & 1][7]);
      float a89 = fmaxf(acc[q >> 1][q & 1][8],  acc[q >> 1][q & 1][9]);
      float aab = fmaxf(acc[q >> 1][q & 1][10], acc[q >> 1][q & 1][11]);
      float acd = fmaxf(acc[q >> 1][q & 1][12], acc[q >> 1][q & 1][13]);
      float aef = fmaxf(acc[q >> 1][q & 1][14], acc[q >> 1][q & 1][15]);
      vm[q] = fmaxf(fmaxf(fmaxf(a01, a23), fmaxf(a45, a67)),
                    fmaxf(fmaxf(a89, aab), fmaxf(acd, aef)));
    }
    float v = fmaxf(fmaxf(vm[0], vm[1]), fmaxf(vm[2], vm[3]));
    #pragma unroll
    for (int off = 1; off < 64; off <<= 1) v = fmaxf(v, __shfl_xor(v, off));
    float msub = v - 96.f;

    #pragma unroll
    for (int rt = 0; rt < 2; ++rt)
      #pragma unroll
      for (int ctl = 0; ctl < 2; ++ctl)
        #pragma unroll
        for (int r = 0; r < 16; ++r) acc[rt][ctl][r] = HEXP2(acc[rt][ctl][r] - msub);

    // col partials: sum over 64 rows of wave tile (reg-local + xor32)
    #pragma unroll
    for (int ctl = 0; ctl < 2; ++ctl) {
      float cp = 0.f;
      #pragma unroll
      for (int r = 0; r < 16; ++r) cp += acc[0][ctl][r] + acc[1][ctl][r];
      cp += __shfl_xor(cp, 32);
      if (h == 0) colbuf[wr * 128 + wc * 64 + ctl * 32 + m] = make_float2(msub, cp);
    }

    // row partials: ctl-add, 2-step butterfly over m-groups (g = m&7 sums 4 cols x
    // 2 ctl = 8 cols), lanes m<16 write 16 srcs/row -> rowbuf2[row][wc*8 + g]
    float rp[2][16];
    #pragma unroll
    for (int rt = 0; rt < 2; ++rt)
      #pragma unroll
      for (int r = 0; r < 16; ++r) {
        float x = acc[rt][0][r] + acc[rt][1][r];
        x += __shfl_xor(x, 8);
        x += __shfl_xor(x, 16);
        rp[rt][r] = x;
      }
    #pragma unroll
    for (int rt = 0; rt < 2; ++rt)
      #pragma unroll
      for (int r = 0; r < 16; ++r)
        if ((m >> 3) == rt)  // lanes m in [rt*8, rt*8+8) write src wc*8 + (m&7)
          rowbuf2[(size_t)(wr * 64 + rt * 32 + (r & 3) + 8 * (r >> 2) + 4 * h) * 20 +
                  wc * 8 + (m & 7)] = rp[rt][r];

    asm volatile("s_waitcnt lgkmcnt(0)" ::: "memory");
    __builtin_amdgcn_s_barrier();
    asm volatile("" ::: "memory");

    // phase2 rows: own row = wr*64 + wc*32 + m; sum 16 srcs (h-redundant)
    {
      const float* rb = rowbuf2 + (size_t)(wr * 64 + wc * 32 + m) * 20;
      float4 q0 = *(const float4*)(rb + 0);
      float4 q1 = *(const float4*)(rb + 4);
      float4 q2 = *(const float4*)(rb + 8);
      float4 q3 = *(const float4*)(rb + 12);
      float s = ((q0.x + q0.y) + (q0.z + q0.w)) + ((q1.x + q1.y) + (q1.z + q1.w))
              + ((q2.x + q2.y) + (q2.z + q2.w)) + ((q3.x + q3.y) + (q3.z + q3.w));
      if (s > 0.f) {
        if (msub > Mr) { Sr = Sr * HEXP2(Mr - msub) + s; Mr = msub; }
        else           { Sr += s * HEXP2(msub - Mr); }
      }
    }
    // phase2 cols: merge wr=0/1 partials -> pC
    if (tid < 128) {
      float2 c0 = colbuf[tid], c1 = colbuf[128 + tid];
      float M = -3.0e38f, L = 0.f;
      if (c0.y > 0.f) { M = c0.x; L = c0.y; }
      if (c1.y > 0.f) {
        if (c1.x > M) { L = L * HEXP2(M - c1.x) + c1.y; M = c1.x; }
        else          { L += c1.y * HEXP2(c1.x - M); }
      }
      pC[(size_t)stripe * N_ + by * 2048 + jj * 128 + tid] = make_float2(M, L);
    }
    asm volatile("s_waitcnt lgkmcnt(0)" ::: "memory");
    __builtin_amdgcn_s_barrier();
    asm volatile("" ::: "memory");
  }

  if (h == 0)
    pR[(size_t)by * N_ + stripe * 128 + wr * 64 + wc * 32 + m] = make_float2(Mr, Sr);
}

// ---------------- merge: rows (8 partials) + cols (128 partials, 4 chains) -> LSE -> loss ----------------
// Accumulates the pre-scaled block sum directly into out[0] (zeroed by prep_pack).
__global__ void merge_kernel(const float2* __restrict__ pR, const float2* __restrict__ pC,
                             const float* __restrict__ diag2, float* __restrict__ out) {
  auto mrg = [](float& M, float& L, float2 w) {
    if (w.y > 0.f) {
      if (w.x > M) { L = L * exp2f(M - w.x) + w.y; M = w.x; }
      else         { L += w.y * exp2f(w.x - M); }
    }
  };
  int idx = blockIdx.x * 256 + threadIdx.x;  // 0..2N-1
  float M = -3.0e38f, L = 0.f;
  int i;
  if (idx < N_) {
    i = idx;
    #pragma unroll
    for (int g = 0; g < 8; ++g) mrg(M, L, pR[(size_t)g * N_ + i]);
  } else {
    i = idx - N_;
    float M1 = -3.0e38f, L1 = 0.f, M2 = -3.0e38f, L2 = 0.f, M3 = -3.0e38f, L3 = 0.f;
    #pragma unroll 4
    for (int s = 0; s < 128; s += 4) {
      mrg(M,  L,  pC[(size_t)(s + 0) * N_ + i]);
      mrg(M1, L1, pC[(size_t)(s + 1) * N_ + i]);
      mrg(M2, L2, pC[(size_t)(s + 2) * N_ + i]);
      mrg(M3, L3, pC[(size_t)(s + 3) * N_ + i]);
    }
    mrg(M, L, make_float2(M1, L1));
    mrg(M, L, make_float2(M2, L2));
    mrg(M, L, make_float2(M3, L3));
  }
  float val = (M + log2f(fmaxf(L, 1e-45f))) - diag2[i];

  __shared__ float red[256];
  red[threadIdx.x] = val;
  __syncthreads();
  #pragma unroll
  for (int s = 128; s > 0; s >>= 1) {
    if (threadIdx.x < s) red[threadIdx.x] += red[threadIdx.x + s];
    __syncthreads();
  }
  if (threadIdx.x == 0)
    atomicAdd(out, red[0] * (0.69314718055994531f / 32768.0f));  // ln2 / (2N)
}

// ---------------- launch ----------------
extern "C" void kernel_launch(void* const* d_in, const int* in_sizes, int n_in,
                              void* d_out, int out_size, void* d_ws, size_t ws_size,
                              hipStream_t stream) {
  const float* img = (const float*)d_in[0];
  const float* txt = (const float*)d_in[1];
  const float* ls  = (const float*)d_in[2];
  float* out = (float*)d_out;

  char* ws = (char*)d_ws;
  short* PA    = (short*)(ws);                 //  8 MB
  short* PB    = (short*)(ws + 8388608);       //  8 MB
  float* diag2 = (float*)(ws + 16777216);      //  64 KB
  float2* pR   = (float2*)(ws + 16843008);     //  1 MB  (8 x N)
  float2* pC   = (float2*)(ws + 17891584);     //  16 MB (128 x N)

  hipLaunchKernelGGL(prep_pack, dim3(512), dim3(1024), 0, stream, img, txt, ls, PA, PB, diag2, out);
  hipLaunchKernelGGL(gemm_stats, dim3(128, 8), dim3(256), 0, stream, PA, PB, pR, pC);
  hipLaunchKernelGGL(merge_kernel, dim3(2 * N_ / 256), dim3(256), 0, stream, pR, pC, diag2, out);
}

// Round 7
// 286.428 us; speedup vs baseline: 1.1511x; 1.1511x over previous
//
#include <hip/hip_runtime.h>

#define N_ 16384
#define D_ 256
#define LOG2E 1.4426950408889634f
#define HEXP2(x) __builtin_amdgcn_exp2f(x)

typedef __attribute__((ext_vector_type(8))) short short8;
typedef __attribute__((ext_vector_type(16))) float floatx16;

typedef __attribute__((address_space(1))) const unsigned int gu32_t;
typedef __attribute__((address_space(3))) unsigned int lu32_t;

__device__ __forceinline__ void async16(const void* g, void* l) {
  __builtin_amdgcn_global_load_lds((gu32_t*)g, (lu32_t*)l, 16, 0, 0);
}

__device__ __forceinline__ unsigned short f2bf(float x) {
  unsigned int u = __float_as_uint(x);
  u += 0x7fffu + ((u >> 16) & 1u);
  return (unsigned short)(u >> 16);
}

// ---------------- prep v2: coalesced reads -> LDS transpose -> coalesced packed writes ----------------
// Block = one G (32 rows x 256 cols), 1024 threads. Thread t handles unit t (16B,
// row = t>>5, kq = t&31). Reads are 32B/lane contiguous (2 float4); packed position
// pos = (kq>>1)*64 + (kq&1)*32 + row stored at pos ^ ((pos>>6)&7) (XOR swizzle,
// involution within each 64-unit block: write ~4-way, linear read conflict-free).
// After one __syncthreads: linear LDS read -> fully coalesced PA/PB writes.
// Exact fp32 diagonal via red2[colgroup][row] scratch, same semantics as before.
__global__ void prep_pack(const float* __restrict__ img, const float* __restrict__ txt,
                          const float* __restrict__ ls, short* __restrict__ PA,
                          short* __restrict__ PB, float* __restrict__ diag2,
                          float* __restrict__ out) {
  __shared__ __align__(16) short8 lds_a[1024];
  __shared__ __align__(16) short8 lds_b[1024];
  __shared__ float red2[32][33];
  const int t = threadIdx.x;   // 0..1023
  const int G = blockIdx.x;    // 0..511
  const int row = t >> 5, kq = t & 31;
  const float s2 = ls[0] * LOG2E;

  const float4* sa = (const float4*)(img + (size_t)G * 8192);
  const float4* sb = (const float4*)(txt + (size_t)G * 8192);
  float4 a0 = sa[2 * t], a1 = sa[2 * t + 1];
  float4 b0 = sb[2 * t], b1 = sb[2 * t + 1];

  short8 oa, ob;
  oa[0] = (short)f2bf(a0.x * s2); oa[1] = (short)f2bf(a0.y * s2);
  oa[2] = (short)f2bf(a0.z * s2); oa[3] = (short)f2bf(a0.w * s2);
  oa[4] = (short)f2bf(a1.x * s2); oa[5] = (short)f2bf(a1.y * s2);
  oa[6] = (short)f2bf(a1.z * s2); oa[7] = (short)f2bf(a1.w * s2);
  ob[0] = (short)f2bf(b0.x); ob[1] = (short)f2bf(b0.y);
  ob[2] = (short)f2bf(b0.z); ob[3] = (short)f2bf(b0.w);
  ob[4] = (short)f2bf(b1.x); ob[5] = (short)f2bf(b1.y);
  ob[6] = (short)f2bf(b1.z); ob[7] = (short)f2bf(b1.w);

  const int pos = (kq >> 1) * 64 + (kq & 1) * 32 + row;
  const int spos = pos ^ ((pos >> 6) & 7);
  lds_a[spos] = oa;
  lds_b[spos] = ob;

  float d = a0.x * b0.x + a0.y * b0.y + a0.z * b0.z + a0.w * b0.w
          + a1.x * b1.x + a1.y * b1.y + a1.z * b1.z + a1.w * b1.w;
  red2[kq][row] = d;
  __syncthreads();

  const int rp = t ^ ((t >> 6) & 7);
  ((short8*)PA)[(size_t)G * 1024 + t] = lds_a[rp];
  ((short8*)PB)[(size_t)G * 1024 + t] = lds_b[rp];

  if (t < 32) {
    float s = 0.f;
    #pragma unroll
    for (int q = 0; q < 32; ++q) s += red2[q][t];
    diag2[G * 32 + t] = s * s2;  // log2-domain scaled diagonal
  }
  if (G == 0 && t == 0) out[0] = 0.f;
}

// ---------------- gemm + stats: A-in-registers, continuous B pipeline ----------------
// KNOWN-GOOD round-5 structure (passed at 170us) byte-for-byte, except the
// XCD-aware block swizzle (T1): nwg=1024 == 0 mod 8 -> bijective remap so each
// XCD's co-resident blocks share ONE by-panel (2MB, L2-fits) instead of ~4-5
// panels (10MB, thrash). Pure index remap, no sync change.
// BANNED until bisected (r3/r4/r6 evidence): 4-buffer single-barrier staging;
// racc register row-accumulation + end transpose; colbuf double-buffer;
// per-wave-private barrier-free staging; setprio.
__global__ __launch_bounds__(256, 2)
void gemm_stats(const short* __restrict__ PA, const short* __restrict__ PB,
                float2* __restrict__ pR, float2* __restrict__ pC) {
  __shared__ __align__(16) char smem[73728];
  // [0,32768): B staging dbuf (2 x 16KB, 16 frags x 1KB each)
  // [32768,71680): rowbuf f32 [wr*64+slot][76] (38912 B)
  // [71680,73728): colbuf float2[2][128]
  float* rowbuf  = (float*)(smem + 32768);
  float2* colbuf = (float2*)(smem + 71680);

  const int tid = threadIdx.x, lane = tid & 63, wv = tid >> 6;
  const int wr = wv >> 1, wc = wv & 1;
  const int m = lane & 31, h = lane >> 5;
  // XCD-aware swizzle: orig%8 picks the XCD (round-robin dispatch); give each
  // XCD one full by-group of 128 contiguous stripes.
  const int orig = blockIdx.x + blockIdx.y * 128;
  const int swz = (orig & 7) * 128 + (orig >> 3);
  const int stripe = swz & 127, by = swz >> 7;

  // ---- A panel into registers: rows stripe*128 + wr*64 .. +64, all K
  short8 areg[2][16];
  #pragma unroll
  for (int g = 0; g < 2; ++g)
    #pragma unroll
    for (int ks = 0; ks < 16; ++ks)
      areg[g][ks] = *(const short8*)(PA +
          ((size_t)((stripe * 4 + wr * 2 + g) * 16 + ks)) * 512 + lane * 8);
  asm volatile("s_waitcnt vmcnt(0)" ::: "memory");

  floatx16 acc[2][2];

  // stage chunk (jj2, c2) -> buffer bufsel. Wave wv stages ks-slice wv for 4 ct frags.
  auto issue = [&](int jj2, int c2, int bufsel) {
    const short* base = PB + ((size_t)((by * 64 + jj2 * 4) * 16) + c2 * 4 + wv) * 512 + lane * 8;
    char* dst = smem + bufsel * 16384 + wv * 1024;
    #pragma unroll
    for (int ct = 0; ct < 4; ++ct)
      async16(base + (size_t)ct * 8192, dst + ct * 4096);
  };
  auto compute = [&](int c, int bufsel) {
    char* base = smem + bufsel * 16384 + lane * 16;
    #pragma unroll
    for (int ksl = 0; ksl < 4; ++ksl) {
      short8 b0 = *(const short8*)(base + ((wc * 2 + 0) * 4 + ksl) * 1024);
      short8 b1 = *(const short8*)(base + ((wc * 2 + 1) * 4 + ksl) * 1024);
      int ks = c * 4 + ksl;  // compile-time under unroll
      acc[0][0] = __builtin_amdgcn_mfma_f32_32x32x16_bf16(areg[0][ks], b0, acc[0][0], 0, 0, 0);
      acc[1][0] = __builtin_amdgcn_mfma_f32_32x32x16_bf16(areg[1][ks], b0, acc[1][0], 0, 0, 0);
      acc[0][1] = __builtin_amdgcn_mfma_f32_32x32x16_bf16(areg[0][ks], b1, acc[0][1], 0, 0, 0);
      acc[1][1] = __builtin_amdgcn_mfma_f32_32x32x16_bf16(areg[1][ks], b1, acc[1][1], 0, 0, 0);
    }
  };

  issue(0, 0, 0);
  issue(0, 1, 1);

  float Mr = -3.0e38f, Sr = 0.f;  // row LSE state: row = stripe*128 + wr*64 + wc*32 + m

  for (int jj = 0; jj < 16; ++jj) {
    #pragma unroll
    for (int rt = 0; rt < 2; ++rt)
      #pragma unroll
      for (int ctl = 0; ctl < 2; ++ctl)
        #pragma unroll
        for (int r = 0; r < 16; ++r) acc[rt][ctl][r] = 0.f;

    #pragma unroll
    for (int c = 0; c < 4; ++c) {
      if (jj == 15 && c == 3) { asm volatile("s_waitcnt vmcnt(0)" ::: "memory"); }
      else                    { asm volatile("s_waitcnt vmcnt(4)" ::: "memory"); }
      __builtin_amdgcn_s_barrier();
      asm volatile("" ::: "memory");
      compute(c, c & 1);
      asm volatile("" ::: "memory");
      __builtin_amdgcn_s_barrier();
      asm volatile("" ::: "memory");
      int nc = c + 2;
      int jj2 = jj + (nc >> 2);
      if (jj2 < 16) issue(jj2, nc & 3, nc & 1);
    }

    // ---- stats. acc[rt][ctl][reg]: row(in tile) = wr*64+rt*32+(reg&3)+8*(reg>>2)+4*h
    //                                col(in tile) = wc*64+ctl*32+m
    // pairwise tree-max (short dependency chains), then wave-wide shfl reduce
    float vm[4];
    #pragma unroll
    for (int q = 0; q < 4; ++q) {
      float a01 = fmaxf(acc[q >> 1][q & 1][0],  acc[q >> 1][q & 1][1]);
      float a23 = fmaxf(acc[q >> 1][q & 1][2],  acc[q >> 1][q & 1][3]);
      float a45 = fmaxf(acc[q >> 1][q & 1][4],  acc[q >> 1][q & 1][5]);
      float a67 = fmaxf(acc[q >> 1][q & 1][6],  acc[q >> 1][q & 1][7]);
      float a89 = fmaxf(acc[q >> 1][q & 1][8],  acc[q >> 1][q & 1][9]);
      float aab = fmaxf(acc[q >> 1][q & 1][10], acc[q >> 1][q & 1][11]);
      float acd = fmaxf(acc[q >> 1][q & 1][12], acc[q >> 1][q & 1][13]);
      float aef = fmaxf(acc[q >> 1][q & 1][14], acc[q >> 1][q & 1][15]);
      vm[q] = fmaxf(fmaxf(fmaxf(a01, a23), fmaxf(a45, a67)),
                    fmaxf(fmaxf(a89, aab), fmaxf(acd, aef)));
    }
    float v = fmaxf(fmaxf(vm[0], vm[1]), fmaxf(vm[2], vm[3]));
    #pragma unroll
    for (int off = 1; off < 64; off <<= 1) v = fmaxf(v, __shfl_xor(v, off));
    float msub = v - 96.f;

    #pragma unroll
    for (int rt = 0; rt < 2; ++rt)
      #pragma unroll
      for (int ctl = 0; ctl < 2; ++ctl)
        #pragma unroll
        for (int r = 0; r < 16; ++r) acc[rt][ctl][r] = HEXP2(acc[rt][ctl][r] - msub);

    // col partials: sum over 64 rows of wave tile (reg-local + xor32)
    #pragma unroll
    for (int ctl = 0; ctl < 2; ++ctl) {
      float cp = 0.f;
      #pragma unroll
      for (int r = 0; r < 16; ++r) cp += acc[0][ctl][r] + acc[1][ctl][r];
      cp += __shfl_xor(cp, 32);
      if (h == 0) colbuf[wr * 128 + wc * 64 + ctl * 32 + m] = make_float2(msub, cp);
    }

    // row partials: ctl-add, pack 4 rows -> float4, rowbuf[(wr*64+slot)*76 + row]
    #pragma unroll
    for (int rt = 0; rt < 2; ++rt)
      #pragma unroll
      for (int rq = 0; rq < 4; ++rq) {
        float4 rp;
        rp.x = acc[rt][0][rq * 4 + 0] + acc[rt][1][rq * 4 + 0];
        rp.y = acc[rt][0][rq * 4 + 1] + acc[rt][1][rq * 4 + 1];
        rp.z = acc[rt][0][rq * 4 + 2] + acc[rt][1][rq * 4 + 2];
        rp.w = acc[rt][0][rq * 4 + 3] + acc[rt][1][rq * 4 + 3];
        *(float4*)&rowbuf[(wr * 64 + wc * 32 + m) * 76 + rt * 32 + rq * 8 + h * 4] = rp;
      }
    asm volatile("s_waitcnt lgkmcnt(0)" ::: "memory");
    __builtin_amdgcn_s_barrier();
    asm volatile("" ::: "memory");

    // phase2 rows: this wave owns rows wc*32+m of the wr pair; halves split slots
    {
      float s = 0.f;
      #pragma unroll
      for (int k = 0; k < 32; ++k)
        s += rowbuf[(wr * 64 + h * 32 + k) * 76 + wc * 32 + m];
      s += __shfl_xor(s, 32);
      if (s > 0.f) {
        if (msub > Mr) { Sr = Sr * HEXP2(Mr - msub) + s; Mr = msub; }
        else           { Sr += s * HEXP2(msub - Mr); }
      }
    }
    // phase2 cols: merge wr=0/1 partials -> pC
    if (tid < 128) {
      float2 c0 = colbuf[tid], c1 = colbuf[128 + tid];
      float M = -3.0e38f, L = 0.f;
      if (c0.y > 0.f) { M = c0.x; L = c0.y; }
      if (c1.y > 0.f) {
        if (c1.x > M) { L = L * HEXP2(M - c1.x) + c1.y; M = c1.x; }
        else          { L += c1.y * HEXP2(c1.x - M); }
      }
      pC[(size_t)stripe * N_ + by * 2048 + jj * 128 + tid] = make_float2(M, L);
    }
    asm volatile("s_waitcnt lgkmcnt(0)" ::: "memory");
    __builtin_amdgcn_s_barrier();
    asm volatile("" ::: "memory");
  }

  if (h == 0)
    pR[(size_t)by * N_ + stripe * 128 + wr * 64 + wc * 32 + m] = make_float2(Mr, Sr);
}

// ---------------- merge: rows (8 partials) + cols (128 partials, 4 chains) -> LSE -> loss ----------------
// Accumulates the pre-scaled block sum directly into out[0] (zeroed by prep_pack).
__global__ void merge_kernel(const float2* __restrict__ pR, const float2* __restrict__ pC,
                             const float* __restrict__ diag2, float* __restrict__ out) {
  auto mrg = [](float& M, float& L, float2 w) {
    if (w.y > 0.f) {
      if (w.x > M) { L = L * exp2f(M - w.x) + w.y; M = w.x; }
      else         { L += w.y * exp2f(w.x - M); }
    }
  };
  int idx = blockIdx.x * 256 + threadIdx.x;  // 0..2N-1
  float M = -3.0e38f, L = 0.f;
  int i;
  if (idx < N_) {
    i = idx;
    #pragma unroll
    for (int g = 0; g < 8; ++g) mrg(M, L, pR[(size_t)g * N_ + i]);
  } else {
    i = idx - N_;
    float M1 = -3.0e38f, L1 = 0.f, M2 = -3.0e38f, L2 = 0.f, M3 = -3.0e38f, L3 = 0.f;
    #pragma unroll 4
    for (int s = 0; s < 128; s += 4) {
      mrg(M,  L,  pC[(size_t)(s + 0) * N_ + i]);
      mrg(M1, L1, pC[(size_t)(s + 1) * N_ + i]);
      mrg(M2, L2, pC[(size_t)(s + 2) * N_ + i]);
      mrg(M3, L3, pC[(size_t)(s + 3) * N_ + i]);
    }
    mrg(M, L, make_float2(M1, L1));
    mrg(M, L, make_float2(M2, L2));
    mrg(M, L, make_float2(M3, L3));
  }
  float val = (M + log2f(fmaxf(L, 1e-45f))) - diag2[i];

  __shared__ float red[256];
  red[threadIdx.x] = val;
  __syncthreads();
  #pragma unroll
  for (int s = 128; s > 0; s >>= 1) {
    if (threadIdx.x < s) red[threadIdx.x] += red[threadIdx.x + s];
    __syncthreads();
  }
  if (threadIdx.x == 0)
    atomicAdd(out, red[0] * (0.69314718055994531f / 32768.0f));  // ln2 / (2N)
}

// ---------------- launch ----------------
extern "C" void kernel_launch(void* const* d_in, const int* in_sizes, int n_in,
                              void* d_out, int out_size, void* d_ws, size_t ws_size,
                              hipStream_t stream) {
  const float* img = (const float*)d_in[0];
  const float* txt = (const float*)d_in[1];
  const float* ls  = (const float*)d_in[2];
  float* out = (float*)d_out;

  char* ws = (char*)d_ws;
  short* PA    = (short*)(ws);                 //  8 MB
  short* PB    = (short*)(ws + 8388608);       //  8 MB
  float* diag2 = (float*)(ws + 16777216);      //  64 KB
  float2* pR   = (float2*)(ws + 16843008);     //  1 MB  (8 x N)
  float2* pC   = (float2*)(ws + 17891584);     //  16 MB (128 x N)

  hipLaunchKernelGGL(prep_pack, dim3(512), dim3(1024), 0, stream, img, txt, ls, PA, PB, diag2, out);
  hipLaunchKernelGGL(gemm_stats, dim3(128, 8), dim3(256), 0, stream, PA, PB, pR, pC);
  hipLaunchKernelGGL(merge_kernel, dim3(2 * N_ / 256), dim3(256), 0, stream, pR, pC, diag2, out);
}

// Round 8
// 242.220 us; speedup vs baseline: 1.3612x; 1.1825x over previous
//
#include <hip/hip_runtime.h>

#define N_ 16384
#define D_ 256
#define LOG2E 1.4426950408889634f
#define HEXP2(x) __builtin_amdgcn_exp2f(x)

typedef __attribute__((ext_vector_type(8))) short short8;
typedef __attribute__((ext_vector_type(16))) float floatx16;

typedef __attribute__((address_space(1))) const unsigned int gu32_t;
typedef __attribute__((address_space(3))) unsigned int lu32_t;

__device__ __forceinline__ void async16(const void* g, void* l) {
  __builtin_amdgcn_global_load_lds((gu32_t*)g, (lu32_t*)l, 16, 0, 0);
}

__device__ __forceinline__ unsigned short f2bf(float x) {
  unsigned int u = __float_as_uint(x);
  u += 0x7fffu + ((u >> 16) & 1u);
  return (unsigned short)(u >> 16);
}

// ---------------- prep: fp32 -> bf16 packed (write-coalesced) + fused exact diag ----------------
// (round-5 version; passed rounds 1, 2, 5. v2 LDS-transpose variant was neutral-to-
// worse in round 7 -> prep reads are not the bottleneck, keep the simpler form.)
__global__ void prep_pack(const float* __restrict__ img, const float* __restrict__ txt,
                          const float* __restrict__ ls, short* __restrict__ PA,
                          short* __restrict__ PB, float* __restrict__ diag2,
                          float* __restrict__ out) {
  const int tid = threadIdx.x;
  const int t = blockIdx.x * 1024 + tid;
  const int m = tid & 31, h = (tid >> 5) & 1, ks = (tid >> 6) & 15;
  const int G = blockIdx.x;
  const int row = G * 32 + m, col = ks * 16 + h * 8;
  const float s2 = ls[0] * LOG2E;
  const float4* sa = (const float4*)(img + (size_t)row * D_ + col);
  const float4* sb = (const float4*)(txt + (size_t)row * D_ + col);
  float4 a0 = sa[0], a1 = sa[1];
  float4 b0 = sb[0], b1 = sb[1];
  short8 oa, ob;
  oa[0] = (short)f2bf(a0.x * s2); oa[1] = (short)f2bf(a0.y * s2);
  oa[2] = (short)f2bf(a0.z * s2); oa[3] = (short)f2bf(a0.w * s2);
  oa[4] = (short)f2bf(a1.x * s2); oa[5] = (short)f2bf(a1.y * s2);
  oa[6] = (short)f2bf(a1.z * s2); oa[7] = (short)f2bf(a1.w * s2);
  ob[0] = (short)f2bf(b0.x); ob[1] = (short)f2bf(b0.y);
  ob[2] = (short)f2bf(b0.z); ob[3] = (short)f2bf(b0.w);
  ob[4] = (short)f2bf(b1.x); ob[5] = (short)f2bf(b1.y);
  ob[6] = (short)f2bf(b1.z); ob[7] = (short)f2bf(b1.w);
  ((short8*)PA)[t] = oa;
  ((short8*)PB)[t] = ob;

  float d = a0.x * b0.x + a0.y * b0.y + a0.z * b0.z + a0.w * b0.w
          + a1.x * b1.x + a1.y * b1.y + a1.z * b1.z + a1.w * b1.w;
  __shared__ float red[32][33];
  red[tid >> 5][m] = d;
  __syncthreads();
  if (tid < 32) {
    float s = 0.f;
    #pragma unroll
    for (int q = 0; q < 32; ++q) s += red[q][tid];
    diag2[G * 32 + tid] = s * s2;  // log2-domain scaled diagonal
  }
  if (t == 0) out[0] = 0.f;
}

// ---------------- gemm + stats: A-in-registers, continuous B pipeline ----------------
// KNOWN-GOOD round-5 structure byte-for-byte (passed at 170us). No XCD swizzle
// (round 7: FETCH unchanged, +6us -> null-to-negative). No setprio (round 2).
// BANNED until bisected (r3/r4/r6): 4-buffer single-barrier staging; racc register
// row-accumulation + end transpose; colbuf double-buffer; per-wave-private
// barrier-free staging.
__global__ __launch_bounds__(256, 2)
void gemm_stats(const short* __restrict__ PA, const short* __restrict__ PB,
                float2* __restrict__ pR, float2* __restrict__ pC) {
  __shared__ __align__(16) char smem[73728];
  // [0,32768): B staging dbuf (2 x 16KB, 16 frags x 1KB each)
  // [32768,71680): rowbuf f32 [wr*64+slot][76] (38912 B)
  // [71680,73728): colbuf float2[2][128]
  float* rowbuf  = (float*)(smem + 32768);
  float2* colbuf = (float2*)(smem + 71680);

  const int tid = threadIdx.x, lane = tid & 63, wv = tid >> 6;
  const int wr = wv >> 1, wc = wv & 1;
  const int m = lane & 31, h = lane >> 5;
  const int stripe = blockIdx.x, by = blockIdx.y;

  // ---- A panel into registers: rows stripe*128 + wr*64 .. +64, all K
  short8 areg[2][16];
  #pragma unroll
  for (int g = 0; g < 2; ++g)
    #pragma unroll
    for (int ks = 0; ks < 16; ++ks)
      areg[g][ks] = *(const short8*)(PA +
          ((size_t)((stripe * 4 + wr * 2 + g) * 16 + ks)) * 512 + lane * 8);
  asm volatile("s_waitcnt vmcnt(0)" ::: "memory");

  floatx16 acc[2][2];

  // stage chunk (jj2, c2) -> buffer bufsel. Wave wv stages ks-slice wv for 4 ct frags.
  auto issue = [&](int jj2, int c2, int bufsel) {
    const short* base = PB + ((size_t)((by * 64 + jj2 * 4) * 16) + c2 * 4 + wv) * 512 + lane * 8;
    char* dst = smem + bufsel * 16384 + wv * 1024;
    #pragma unroll
    for (int ct = 0; ct < 4; ++ct)
      async16(base + (size_t)ct * 8192, dst + ct * 4096);
  };
  auto compute = [&](int c, int bufsel) {
    char* base = smem + bufsel * 16384 + lane * 16;
    #pragma unroll
    for (int ksl = 0; ksl < 4; ++ksl) {
      short8 b0 = *(const short8*)(base + ((wc * 2 + 0) * 4 + ksl) * 1024);
      short8 b1 = *(const short8*)(base + ((wc * 2 + 1) * 4 + ksl) * 1024);
      int ks = c * 4 + ksl;  // compile-time under unroll
      acc[0][0] = __builtin_amdgcn_mfma_f32_32x32x16_bf16(areg[0][ks], b0, acc[0][0], 0, 0, 0);
      acc[1][0] = __builtin_amdgcn_mfma_f32_32x32x16_bf16(areg[1][ks], b0, acc[1][0], 0, 0, 0);
      acc[0][1] = __builtin_amdgcn_mfma_f32_32x32x16_bf16(areg[0][ks], b1, acc[0][1], 0, 0, 0);
      acc[1][1] = __builtin_amdgcn_mfma_f32_32x32x16_bf16(areg[1][ks], b1, acc[1][1], 0, 0, 0);
    }
  };

  issue(0, 0, 0);
  issue(0, 1, 1);

  float Mr = -3.0e38f, Sr = 0.f;  // row LSE state: row = stripe*128 + wr*64 + wc*32 + m

  for (int jj = 0; jj < 16; ++jj) {
    #pragma unroll
    for (int rt = 0; rt < 2; ++rt)
      #pragma unroll
      for (int ctl = 0; ctl < 2; ++ctl)
        #pragma unroll
        for (int r = 0; r < 16; ++r) acc[rt][ctl][r] = 0.f;

    #pragma unroll
    for (int c = 0; c < 4; ++c) {
      if (jj == 15 && c == 3) { asm volatile("s_waitcnt vmcnt(0)" ::: "memory"); }
      else                    { asm volatile("s_waitcnt vmcnt(4)" ::: "memory"); }
      __builtin_amdgcn_s_barrier();
      asm volatile("" ::: "memory");
      compute(c, c & 1);
      asm volatile("" ::: "memory");
      __builtin_amdgcn_s_barrier();
      asm volatile("" ::: "memory");
      int nc = c + 2;
      int jj2 = jj + (nc >> 2);
      if (jj2 < 16) issue(jj2, nc & 3, nc & 1);
    }

    // ---- stats. acc[rt][ctl][reg]: row(in tile) = wr*64+rt*32+(reg&3)+8*(reg>>2)+4*h
    //                                col(in tile) = wc*64+ctl*32+m
    // pairwise tree-max (short dependency chains), then wave-wide shfl reduce
    float vm[4];
    #pragma unroll
    for (int q = 0; q < 4; ++q) {
      float a01 = fmaxf(acc[q >> 1][q & 1][0],  acc[q >> 1][q & 1][1]);
      float a23 = fmaxf(acc[q >> 1][q & 1][2],  acc[q >> 1][q & 1][3]);
      float a45 = fmaxf(acc[q >> 1][q & 1][4],  acc[q >> 1][q & 1][5]);
      float a67 = fmaxf(acc[q >> 1][q & 1][6],  acc[q >> 1][q & 1][7]);
      float a89 = fmaxf(acc[q >> 1][q & 1][8],  acc[q >> 1][q & 1][9]);
      float aab = fmaxf(acc[q >> 1][q & 1][10], acc[q >> 1][q & 1][11]);
      float acd = fmaxf(acc[q >> 1][q & 1][12], acc[q >> 1][q & 1][13]);
      float aef = fmaxf(acc[q >> 1][q & 1][14], acc[q >> 1][q & 1][15]);
      vm[q] = fmaxf(fmaxf(fmaxf(a01, a23), fmaxf(a45, a67)),
                    fmaxf(fmaxf(a89, aab), fmaxf(acd, aef)));
    }
    float v = fmaxf(fmaxf(vm[0], vm[1]), fmaxf(vm[2], vm[3]));
    #pragma unroll
    for (int off = 1; off < 64; off <<= 1) v = fmaxf(v, __shfl_xor(v, off));
    float msub = v - 96.f;

    #pragma unroll
    for (int rt = 0; rt < 2; ++rt)
      #pragma unroll
      for (int ctl = 0; ctl < 2; ++ctl)
        #pragma unroll
        for (int r = 0; r < 16; ++r) acc[rt][ctl][r] = HEXP2(acc[rt][ctl][r] - msub);

    // col partials: sum over 64 rows of wave tile (reg-local + xor32)
    #pragma unroll
    for (int ctl = 0; ctl < 2; ++ctl) {
      float cp = 0.f;
      #pragma unroll
      for (int r = 0; r < 16; ++r) cp += acc[0][ctl][r] + acc[1][ctl][r];
      cp += __shfl_xor(cp, 32);
      if (h == 0) colbuf[wr * 128 + wc * 64 + ctl * 32 + m] = make_float2(msub, cp);
    }

    // row partials: ctl-add, pack 4 rows -> float4, rowbuf[(wr*64+slot)*76 + row]
    #pragma unroll
    for (int rt = 0; rt < 2; ++rt)
      #pragma unroll
      for (int rq = 0; rq < 4; ++rq) {
        float4 rp;
        rp.x = acc[rt][0][rq * 4 + 0] + acc[rt][1][rq * 4 + 0];
        rp.y = acc[rt][0][rq * 4 + 1] + acc[rt][1][rq * 4 + 1];
        rp.z = acc[rt][0][rq * 4 + 2] + acc[rt][1][rq * 4 + 2];
        rp.w = acc[rt][0][rq * 4 + 3] + acc[rt][1][rq * 4 + 3];
        *(float4*)&rowbuf[(wr * 64 + wc * 32 + m) * 76 + rt * 32 + rq * 8 + h * 4] = rp;
      }
    asm volatile("s_waitcnt lgkmcnt(0)" ::: "memory");
    __builtin_amdgcn_s_barrier();
    asm volatile("" ::: "memory");

    // phase2 rows: this wave owns rows wc*32+m of the wr pair; halves split slots
    {
      float s = 0.f;
      #pragma unroll
      for (int k = 0; k < 32; ++k)
        s += rowbuf[(wr * 64 + h * 32 + k) * 76 + wc * 32 + m];
      s += __shfl_xor(s, 32);
      if (s > 0.f) {
        if (msub > Mr) { Sr = Sr * HEXP2(Mr - msub) + s; Mr = msub; }
        else           { Sr += s * HEXP2(msub - Mr); }
      }
    }
    // phase2 cols: merge wr=0/1 partials -> pC
    if (tid < 128) {
      float2 c0 = colbuf[tid], c1 = colbuf[128 + tid];
      float M = -3.0e38f, L = 0.f;
      if (c0.y > 0.f) { M = c0.x; L = c0.y; }
      if (c1.y > 0.f) {
        if (c1.x > M) { L = L * HEXP2(M - c1.x) + c1.y; M = c1.x; }
        else          { L += c1.y * HEXP2(c1.x - M); }
      }
      pC[(size_t)stripe * N_ + by * 2048 + jj * 128 + tid] = make_float2(M, L);
    }
    asm volatile("s_waitcnt lgkmcnt(0)" ::: "memory");
    __builtin_amdgcn_s_barrier();
    asm volatile("" ::: "memory");
  }

  if (h == 0)
    pR[(size_t)by * N_ + stripe * 128 + wr * 64 + wc * 32 + m] = make_float2(Mr, Sr);
}

// ---------------- merge v2: parallelized (was 128 blocks = 0.5/CU with 128-long
// latency chains; now 576 blocks, 16-step chains, 8 threads/col + LDS combine) ----
// blocks [0,64): rows -- 1 thread/row, 8 partials.
// blocks [64,576): cols -- 32 cols/block, 8 threads/col x 16 partials each,
//   sub-results merged in LDS by the first 32 threads.
// Accumulates the pre-scaled block sum directly into out[0] (zeroed by prep_pack).
__global__ void merge_kernel(const float2* __restrict__ pR, const float2* __restrict__ pC,
                             const float* __restrict__ diag2, float* __restrict__ out) {
  auto mrg = [](float& M, float& L, float2 w) {
    if (w.y > 0.f) {
      if (w.x > M) { L = L * exp2f(M - w.x) + w.y; M = w.x; }
      else         { L += w.y * exp2f(w.x - M); }
    }
  };
  const int b = blockIdx.x, tid = threadIdx.x;
  float val = 0.f;

  if (b < 64) {
    // ---- rows: i = b*256 + tid, 8 partials (coalesced: consecutive tid -> consecutive i)
    int i = b * 256 + tid;
    float M = -3.0e38f, L = 0.f;
    #pragma unroll
    for (int g = 0; g < 8; ++g) mrg(M, L, pR[(size_t)g * N_ + i]);
    val = (M + log2f(fmaxf(L, 1e-45f))) - diag2[i];
  } else {
    // ---- cols: block handles 32 cols; thread (grp = tid>>5, c = tid&31) reduces
    // slices [grp*16, grp*16+16) of col i. Loads coalesced per half-wave.
    int cb = b - 64;                 // 0..511
    int i = cb * 32 + (tid & 31);
    int s0 = (tid >> 5) * 16;
    float M = -3.0e38f, L = 0.f;
    #pragma unroll
    for (int k = 0; k < 16; ++k) mrg(M, L, pC[(size_t)(s0 + k) * N_ + i]);
    __shared__ float2 part[8][32];
    part[tid >> 5][tid & 31] = make_float2(M, L);
    __syncthreads();
    if (tid < 32) {
      float M2 = -3.0e38f, L2 = 0.f;
      #pragma unroll
      for (int q = 0; q < 8; ++q) mrg(M2, L2, part[q][tid]);
      val = (M2 + log2f(fmaxf(L2, 1e-45f))) - diag2[cb * 32 + tid];
    }
  }

  __shared__ float red[256];
  red[tid] = val;
  __syncthreads();
  #pragma unroll
  for (int s = 128; s > 0; s >>= 1) {
    if (tid < s) red[tid] += red[tid + s];
    __syncthreads();
  }
  if (tid == 0)
    atomicAdd(out, red[0] * (0.69314718055994531f / 32768.0f));  // ln2 / (2N)
}

// ---------------- launch ----------------
extern "C" void kernel_launch(void* const* d_in, const int* in_sizes, int n_in,
                              void* d_out, int out_size, void* d_ws, size_t ws_size,
                              hipStream_t stream) {
  const float* img = (const float*)d_in[0];
  const float* txt = (const float*)d_in[1];
  const float* ls  = (const float*)d_in[2];
  float* out = (float*)d_out;

  char* ws = (char*)d_ws;
  short* PA    = (short*)(ws);                 //  8 MB
  short* PB    = (short*)(ws + 8388608);       //  8 MB
  float* diag2 = (float*)(ws + 16777216);      //  64 KB
  float2* pR   = (float2*)(ws + 16843008);     //  1 MB  (8 x N)
  float2* pC   = (float2*)(ws + 17891584);     //  16 MB (128 x N)

  hipLaunchKernelGGL(prep_pack, dim3(512), dim3(1024), 0, stream, img, txt, ls, PA, PB, diag2, out);
  hipLaunchKernelGGL(gemm_stats, dim3(128, 8), dim3(256), 0, stream, PA, PB, pR, pC);
  hipLaunchKernelGGL(merge_kernel, dim3(576), dim3(256), 0, stream, pR, pC, diag2, out);
}